// Round 6
// baseline (142.704 us; speedup 1.0000x reference)
//
#include <hip/hip_runtime.h>

// SSIM, N=32 images 512x512 fp32, 11x11 Gaussian (separable via rank-1
// window), zero pad, scalar mean output.
//
// R15: ONE WAVE = ONE BLOCK. R14 post-mortem: prefetch depth-2 changed
// nothing (44.3 vs 44.0us, VALUBusy 43.5 vs 43.9) -> load distance was not
// the stall. Counter math: 500 cy/iter issued per wave, occupancy 18% =
// 1.45 resident waves/SIMD, per-wave busy 30%. At 1.45 waves/SIMD every
// per-wave stall lands ~1:1 on the wall clock -- all four structures
// (R9/R11/R13/R14) were RESIDENT-WAVE STARVED, which is why they all pin
// at ~43us regardless of schedule. Resources allow much more (VGPR 80 ->
// 6 waves/SIMD, LDS 14KB -> 11 blocks); the limiter is the grid (2.5
// 4-wave blocks/CU) and block-level co-scheduling/tail.
// Fix: waves are already independent (wave-private LDS ring, no main-loop
// barriers since R12) -- launch each as its own 64-thread block:
//   grid (80,32) = 2560 blocks = 10 blocks/CU, 3.5KB LDS each ->
//   resident cap ~16 workgroups/CU = 4 waves/SIMD (~2.7x residency).
//   seg = bx&3 (fast-varying) so a chunk's 4 segments are L2-adjacent.
//   Final reduction: wave shuffle + one atomicAdd; ZERO __syncthreads.
// Per-wave program byte-identical to R14 (iso-work: isolates residency).
// R8+ kept: packed fp32 (v_pk_*) on (s,d)=(x+y,x-y), M=2 cols/thread,
// 3-slot LDS ring (write->read distance 2), depth-2 global prefetch,
// 7x ds_read_b128 horizontal window, 12-slot register vertical ring,
// static-index discipline (unroll-12 inner, %12 %3 %2 static, outer
// `#pragma unroll 1` -- R10 lesson).

typedef float v2f __attribute__((ext_vector_type(2)));
typedef float v4f __attribute__((ext_vector_type(4)));

#define IMG_H 512
#define IMG_W 512
#define NIMG  32
#define NT    64
#define RROWS 26
#define NCHX  20             // ceil(512/26)
#define ITERS 36             // RROWS+10 = 3 x 12 exactly
// per-wave LDS slot: idx 0..139 hold (s,d) of cols C0-6 .. C0+133
// (idx i <-> col C0-6+i). 140 used, pad stride to 144 v2f (1152 B).
#define SEGW  144

#define C1F  1.0e-4f
#define C2F  9.0e-4f
#define EPSF 1.0e-8f

static __device__ __forceinline__ v2f pkfma(float s, v2f a, v2f b) {
    v2f sv = {s, s};
    return __builtin_elementwise_fma(sv, a, b);   // -> v_pk_fma_f32
}

__global__ __launch_bounds__(NT) void ssim_kernel(
    const float* __restrict__ xg, const float* __restrict__ yg,
    const float* __restrict__ wg, float* __restrict__ out)
{
    const int lane = threadIdx.x;       // 0..63
    const int bx   = blockIdx.x;        // 0..79: seg fast, chunk slow
    const int seg  = bx & 3;            // column segment 0..3
    const int chnk = bx >> 2;           // row chunk 0..19
    const int img  = blockIdx.y;        // 0..31
    const int r0   = chnk * RROWS;
    const int C0   = 128 * seg;         // segment col base
    const int cown = C0 + 2 * lane;     // owned cols cown, cown+1
    const int c0l  = 2 * lane;          // local LDS read base (idx units)

    const float* xb = xg + (size_t)img * (IMG_H * IMG_W);
    const float* yb = yg + (size_t)img * (IMG_H * IMG_W);

    __shared__ alignas(16) v2f seg3[3][SEGW];   // 3-slot ring, 3.5KB

    // 1D taps = row sums of normalized 2D window -> SGPRs via readfirstlane.
    float rs = 0.f;
    if (lane < 11) {
        #pragma unroll
        for (int j = 0; j < 11; ++j) rs += wg[lane * 11 + j];
    }
    float g[11];
    #pragma unroll
    for (int k = 0; k < 11; ++k) {
        int gi = __shfl(__float_as_int(rs), k, 64);
        g[k] = __int_as_float(__builtin_amdgcn_readfirstlane(gi));
    }

    const v2f z2 = {0.f, 0.f};

    // halo duty: lanes 0..2 left (cols C0-6+2*lane), lanes 61..63 right
    // (cols C0+128+2*(lane-61)). Out-of-image -> z2 via range guard.
    const bool isH = (lane < 3) || (lane >= 61);
    const int  hcol = (lane < 3) ? (C0 - 6 + 2 * lane)
                                 : (C0 + 128 + 2 * (lane - 61));
    const int  hidx = (lane < 3) ? (2 * lane) : (134 + 2 * (lane - 61));

    // pending-row register sets, depth 2
    v2f px0, py0, hx0, hy0;
    v2f px1, py1, hx1, hy1;

#define LOADROW(ROW, SUF) do {                                             \
        const int r_ = (ROW);                                              \
        px##SUF = z2; py##SUF = z2; hx##SUF = z2; hy##SUF = z2;            \
        if ((unsigned)r_ < IMG_H) {                                        \
            const float* xr = xb + (size_t)r_ * IMG_W;                     \
            const float* yr = yb + (size_t)r_ * IMG_W;                     \
            px##SUF = *(const v2f*)(xr + cown);                            \
            py##SUF = *(const v2f*)(yr + cown);                            \
            if (isH && (unsigned)hcol < IMG_W) {                           \
                hx##SUF = *(const v2f*)(xr + hcol);                        \
                hy##SUF = *(const v2f*)(yr + hcol);                        \
            }                                                              \
        }                                                                  \
    } while (0)

#define WRITESLOT(SL, SUF) do {                                            \
        const v2f sv_ = px##SUF + py##SUF;   /* v_pk_add_f32 */            \
        const v2f dv_ = px##SUF - py##SUF;                                 \
        v4f st_ = {sv_.x, dv_.x, sv_.y, dv_.y};                            \
        *(v4f*)&seg3[(SL)][6 + c0l] = st_;                                 \
        if (isH) {                                                         \
            const v2f hs_ = hx##SUF + hy##SUF;                             \
            const v2f hd_ = hx##SUF - hy##SUF;                             \
            v4f ht_ = {hs_.x, hd_.x, hs_.y, hd_.y};                        \
            *(v4f*)&seg3[(SL)][hidx] = ht_;                                \
        }                                                                  \
    } while (0)

    // prologue: rows 0,1 (r0-5, r0-4) -> slots 0,1; rows 2,3 pending P0,P1.
    LOADROW(r0 - 5, 0);
    LOADROW(r0 - 4, 1);
    WRITESLOT(0, 0);
    WRITESLOT(1, 1);
    LOADROW(r0 - 3, 0);     // P0 = row 2
    LOADROW(r0 - 2, 1);     // P1 = row 3

    // vertical register rings, 12 slots (slot 11+1 pad for static %12)
    v2f rSD[12][2], rQ[12][2];

    float acc = 0.f;

    #pragma unroll 1
    for (int base = 0; base < ITERS; base += 12) {
        #pragma unroll
        for (int s = 0; s < 12; ++s) {
            const int i = base + s;     // streamed-row index; i%12==s,
                                        // i%3==s%3, i%2==s%2 (base %12==0)

            // ---- read row i's window: slot written at iter i-2 ----
            v4f w4r[7];
            #pragma unroll
            for (int m = 0; m < 7; ++m)
                w4r[m] = *(const v4f*)&seg3[s % 3][c0l + 2 * m];

            // ---- stage row i+2 (loaded at iter i-2) ----
            if (i <= ITERS - 3) {               // row i+2 exists/needed
                if (s % 2 == 0) WRITESLOT((s + 2) % 3, 0);
                else            WRITESLOT((s + 2) % 3, 1);
            }

            // ---- issue loads for row i+4 (consumed at iter i+2) ----
            if (i <= ITERS - 5) {               // row i+4 needed
                if (s % 2 == 0) LOADROW(r0 - 5 + i + 4, 0);
                else            LOADROW(r0 - 5 + i + 4, 1);
            }

            // ---- horizontal conv of row i from w4r ----
            // window element j (0..13) at idx c0l+j (col cown-6+j)
            v2f hA = z2, hB = z2, qA = z2, qB = z2;
            #pragma unroll
            for (int m = 0; m < 7; ++m) {
                const v4f w4 = w4r[m];
                const v2f e0 = {w4.x, w4.y};   // j = 2m
                const v2f e1 = {w4.z, w4.w};   // j = 2m+1
                {
                    const int j = 2 * m;
                    if (j >= 1) {
                        const v2f f0 = e0 * e0;          // v_pk_mul_f32
                        if (j <= 11) {
                            hA = pkfma(g[j - 1], e0, hA);
                            qA = pkfma(g[j - 1], f0, qA);
                        }
                        if (j >= 2) {
                            hB = pkfma(g[j - 2], e0, hB);
                            qB = pkfma(g[j - 2], f0, qB);
                        }
                    }
                }
                {
                    const int j = 2 * m + 1;
                    if (j <= 12) {
                        const v2f f1 = e1 * e1;
                        if (j <= 11) {
                            hA = pkfma(g[j - 1], e1, hA);
                            qA = pkfma(g[j - 1], f1, qA);
                        }
                        if (j >= 2) {
                            hB = pkfma(g[j - 2], e1, hB);
                            qB = pkfma(g[j - 2], f1, qB);
                        }
                    }
                }
            }
            rSD[s][0] = hA; rSD[s][1] = hB;
            rQ[s][0]  = qA; rQ[s][1]  = qB;

            // ---- vertical conv + SSIM epilogue (output row r0 + i - 10) ----
            if (i >= 10) {                       // wave-uniform
                const int orow = r0 + i - 10;
                if (orow < IMG_H) {              // wave-uniform tail guard
                    #pragma unroll
                    for (int cc = 0; cc < 2; ++cc) {
                        v2f mSD = z2, mQ = z2;
                        #pragma unroll
                        for (int j = 0; j < 11; ++j) {
                            // input rows i-10+j -> ring slot (i+2+j)%12
                            const int sl = (s + 2 + j) % 12;   // static
                            mSD = pkfma(g[j], rSD[sl][cc], mSD);
                            mQ  = pkfma(g[j], rQ[sl][cc],  mQ);
                        }
                        const v2f t2 = mSD * mSD;      // (mS^2, mD^2)
                        const float a    = 0.5f  * (t2.x + t2.y); // mx2+my2
                        const float muxy = 0.25f * (t2.x - t2.y); // mx*my
                        const float ep   = 0.5f  * (mQ.x + mQ.y); // Ex2+Ey2
                        const float eq   = 0.25f * (mQ.x - mQ.y); // Exy
                        const float sxy  = eq - muxy;
                        const float ssum = ep - a;
                        const float num  = fmaf(2.f, muxy, C1F) * fmaf(2.f, sxy, C2F);
                        const float den  = (a + C1F) * (ssum + C2F);
                        float v = num * __builtin_amdgcn_rcpf(den + EPSF);
                        acc += fminf(fmaxf(v, 0.f), 1.f);
                    }
                }
            }
        }
    }

    // single-wave block: shuffle-reduce, one atomic. No barriers anywhere.
    #pragma unroll
    for (int off = 32; off > 0; off >>= 1)
        acc += __shfl_down(acc, off, 64);
    if (lane == 0)
        atomicAdd(out, acc * (1.0f / (float)((size_t)NIMG * IMG_H * IMG_W)));
}

extern "C" void kernel_launch(void* const* d_in, const int* in_sizes, int n_in,
                              void* d_out, int out_size, void* d_ws, size_t ws_size,
                              hipStream_t stream) {
    const float* x = (const float*)d_in[0];
    const float* y = (const float*)d_in[1];
    const float* w = (const float*)d_in[2];
    float* out = (float*)d_out;

    // d_out is re-poisoned to 0xAA before every timed launch; zero it first.
    hipMemsetAsync(out, 0, sizeof(float), stream);

    dim3 grid(NCHX * 4, NIMG);    // (80, 32) = 2560 single-wave blocks
    ssim_kernel<<<grid, dim3(NT), 0, stream>>>(x, y, w, out);
}

// Round 7
// 120.602 us; speedup vs baseline: 1.1833x; 1.1833x over previous
//
#include <hip/hip_runtime.h>

// SSIM, N=32 images 512x512 fp32, 11x11 Gaussian (separable via rank-1
// window), zero pad, scalar mean output.
//
// R16: REGISTER DIET -> REAL OCCUPANCY. Rounds 9-15 post-mortem: every
// config pinned at ~8 waves/CU because the 96-float vertical ring lives in
// AGPRs (rocprof VGPR_Count hides it: R12 showed "64" with 96+ floats of
// ring state). Unified gfx950 budget: ~80 VGPR + ~96 AGPR = ~176 regs ->
// 2 waves/SIMD hard cap. All grid/block/schedule moves (R11/R13/R14/R15)
// were fake occupancy -- the register file was the limiter all along.
// Fix: M=1 col/thread (was 2). Ring 96 -> 48 floats, pendings 16 -> 8;
// static tally ~100-110 unified -> 4 waves/SIMD, enforced by
// __launch_bounds__(NT, 4) (reg budget 128).
//  - wave covers 64 cols; 8 segments per row; 4-wave block = same chunk,
//    4 adjacent segments (L2 row sharing).
//  - horizontal conv: 11 x ds_read_b64 (e[j]=(s,d) of col c-5+j), 11
//    pk_mul squares + 22 pk_fma. Squares not shared across cols (+18%/col).
//  - RROWS=38 -> ITERS=48=4x12: %12 %3 %2 static under inner unroll-12,
//    outer `#pragma unroll 1` (R10 lesson). Grid (28,32)=896 blocks =
//    3584 waves ~= 0.9x the 4096 resident slots at 4/SIMD: single cohort.
//  - work/image = 14x48x512 col-iters = 0.93x R14.
// Kept: wave-private 3-slot LDS ring (write->read distance 2, R13),
// depth-2 global prefetch (R14), (s,d)=(x+y,x-y) packed fp32 trick,
// 12-slot register vertical ring, same epilogue, no main-loop barriers.

typedef float v2f __attribute__((ext_vector_type(2)));

#define IMG_H 512
#define IMG_W 512
#define NIMG  32
#define NT    256
#define RROWS 38
#define NCHNK 14             // ceil(512/38): last chunk outputs 18 rows
#define ITERS 48             // RROWS+10 = 4 x 12 exactly
// per-wave LDS slot: idx 0..73 hold (s,d) of cols C0-5 .. C0+68
// (idx k <-> col C0-5+k). 74 used, pad stride to 80 v2f (640 B).
#define SLOTW 80

#define C1F  1.0e-4f
#define C2F  9.0e-4f
#define EPSF 1.0e-8f

static __device__ __forceinline__ v2f pkfma(float s, v2f a, v2f b) {
    v2f sv = {s, s};
    return __builtin_elementwise_fma(sv, a, b);   // -> v_pk_fma_f32
}

__global__ __launch_bounds__(NT, 4) void ssim_kernel(
    const float* __restrict__ xg, const float* __restrict__ yg,
    const float* __restrict__ wg, float* __restrict__ out)
{
    const int t    = threadIdx.x;       // 0..255
    const int lane = t & 63;
    const int wv   = t >> 6;            // wave id 0..3
    const int bx   = blockIdx.x;        // 0..27
    const int img  = blockIdx.y;        // 0..31
    const int chnk = bx >> 1;           // 0..13
    const int seg  = ((bx & 1) << 2) | wv;   // 0..7: block = 4 adjacent segs
    const int r0   = chnk * RROWS;
    const int C0   = seg * 64;          // segment col base
    const int cown = C0 + lane;         // owned col

    const float* xb = xg + (size_t)img * (IMG_H * IMG_W);
    const float* yb = yg + (size_t)img * (IMG_H * IMG_W);

    __shared__ alignas(16) v2f seg3[4][3][SLOTW];   // 4 waves x 3 slots, 7.5KB
    __shared__ float wredS[4];

    // 1D taps = row sums of normalized 2D window -> SGPRs via readfirstlane.
    float rs = 0.f;
    if (lane < 11) {
        #pragma unroll
        for (int j = 0; j < 11; ++j) rs += wg[lane * 11 + j];
    }
    float g[11];
    #pragma unroll
    for (int k = 0; k < 11; ++k) {
        int gi = __shfl(__float_as_int(rs), k, 64);
        g[k] = __int_as_float(__builtin_amdgcn_readfirstlane(gi));
    }

    // halo duty: lanes 0..4 left (col C0-5+lane, idx lane), lanes 59..63
    // right (col C0+64+(lane-59), idx lane+10). Out-of-image -> 0.
    const bool isH  = (lane < 5) || (lane >= 59);
    const int  hcol = (lane < 5) ? (C0 - 5 + lane) : (C0 + 64 + (lane - 59));
    const int  hidx = (lane < 5) ? lane : (lane + 10);

    // pending-row registers, depth 2 (scalars: M=1)
    float px0, py0, hx0, hy0;
    float px1, py1, hx1, hy1;

#define LOADROW(ROW, SUF) do {                                             \
        const int r_ = (ROW);                                              \
        px##SUF = 0.f; py##SUF = 0.f; hx##SUF = 0.f; hy##SUF = 0.f;        \
        if ((unsigned)r_ < IMG_H) {                                        \
            const float* xr = xb + (size_t)r_ * IMG_W;                     \
            const float* yr = yb + (size_t)r_ * IMG_W;                     \
            px##SUF = xr[cown];                                            \
            py##SUF = yr[cown];                                            \
            if (isH && (unsigned)hcol < IMG_W) {                           \
                hx##SUF = xr[hcol];                                        \
                hy##SUF = yr[hcol];                                        \
            }                                                              \
        }                                                                  \
    } while (0)

#define WRITESLOT(SL, SUF) do {                                            \
        v2f sd_ = {px##SUF + py##SUF, px##SUF - py##SUF};                  \
        seg3[wv][(SL)][5 + lane] = sd_;                                    \
        if (isH) {                                                         \
            v2f hsd_ = {hx##SUF + hy##SUF, hx##SUF - hy##SUF};             \
            seg3[wv][(SL)][hidx] = hsd_;                                   \
        }                                                                  \
    } while (0)

    // prologue: rows 0,1 (r0-5, r0-4) -> slots 0,1; rows 2,3 pending P0,P1.
    LOADROW(r0 - 5, 0);
    LOADROW(r0 - 4, 1);
    WRITESLOT(0, 0);
    WRITESLOT(1, 1);
    LOADROW(r0 - 3, 0);     // P0 = streamed row 2
    LOADROW(r0 - 2, 1);     // P1 = streamed row 3

    // vertical register rings, 12 slots (11 + 1 pad for static %12): 48 fl
    v2f rSD[12], rQ[12];

    float acc = 0.f;

    #pragma unroll 1
    for (int base = 0; base < ITERS; base += 12) {
        #pragma unroll
        for (int s = 0; s < 12; ++s) {
            const int i = base + s;     // streamed-row index; i%12==s,
                                        // i%3==s%3, i%2==s%2 (base %12==0)

            // ---- read row i's window: slot written at iter i-2 ----
            // e[j] = (s,d) of col cown-5+j at idx lane+j, 11x ds_read_b64
            v2f e[11];
            #pragma unroll
            for (int j = 0; j < 11; ++j)
                e[j] = seg3[wv][s % 3][lane + j];

            // ---- stage row i+2 (loaded at iter i-2) ----
            if (i <= ITERS - 3) {
                if (s % 2 == 0) WRITESLOT((s + 2) % 3, 0);
                else            WRITESLOT((s + 2) % 3, 1);
            }

            // ---- issue loads for row i+4 (consumed at iter i+2) ----
            if (i <= ITERS - 5) {
                if (s % 2 == 0) LOADROW(r0 - 5 + i + 4, 0);
                else            LOADROW(r0 - 5 + i + 4, 1);
            }

            // ---- horizontal conv of row i ----
            v2f hSD = {0.f, 0.f}, hQ = {0.f, 0.f};
            #pragma unroll
            for (int j = 0; j < 11; ++j) {
                const v2f f = e[j] * e[j];          // v_pk_mul_f32
                hSD = pkfma(g[j], e[j], hSD);
                hQ  = pkfma(g[j], f,    hQ);
            }
            rSD[s] = hSD;
            rQ[s]  = hQ;

            // ---- vertical conv + SSIM epilogue (output row r0 + i - 10) ----
            if (i >= 10) {                       // wave-uniform
                const int orow = r0 + i - 10;
                if (orow < IMG_H) {              // wave-uniform tail guard
                    v2f mSD = {0.f, 0.f}, mQ = {0.f, 0.f};
                    #pragma unroll
                    for (int j = 0; j < 11; ++j) {
                        // input rows i-10+j -> ring slot (i+2+j)%12
                        const int sl = (s + 2 + j) % 12;   // static
                        mSD = pkfma(g[j], rSD[sl], mSD);
                        mQ  = pkfma(g[j], rQ[sl],  mQ);
                    }
                    const v2f t2 = mSD * mSD;      // (mS^2, mD^2)
                    const float a    = 0.5f  * (t2.x + t2.y); // mx2+my2
                    const float muxy = 0.25f * (t2.x - t2.y); // mx*my
                    const float ep   = 0.5f  * (mQ.x + mQ.y); // Ex2+Ey2
                    const float eq   = 0.25f * (mQ.x - mQ.y); // Exy
                    const float sxy  = eq - muxy;
                    const float ssum = ep - a;
                    const float num  = fmaf(2.f, muxy, C1F) * fmaf(2.f, sxy, C2F);
                    const float den  = (a + C1F) * (ssum + C2F);
                    float v = num * __builtin_amdgcn_rcpf(den + EPSF);
                    acc += fminf(fmaxf(v, 0.f), 1.f);
                }
            }
        }
    }

    // block reduction: wave shuffle, 4 slots in LDS, one atomic per block.
    // (The only __syncthreads in the kernel -- at the very end.)
    #pragma unroll
    for (int off = 32; off > 0; off >>= 1)
        acc += __shfl_down(acc, off, 64);
    if (lane == 0) wredS[wv] = acc;
    __syncthreads();
    if (t == 0) {
        const float tot = (wredS[0] + wredS[1]) + (wredS[2] + wredS[3]);
        atomicAdd(out, tot * (1.0f / (float)((size_t)NIMG * IMG_H * IMG_W)));
    }
}

extern "C" void kernel_launch(void* const* d_in, const int* in_sizes, int n_in,
                              void* d_out, int out_size, void* d_ws, size_t ws_size,
                              hipStream_t stream) {
    const float* x = (const float*)d_in[0];
    const float* y = (const float*)d_in[1];
    const float* w = (const float*)d_in[2];
    float* out = (float*)d_out;

    // d_out is re-poisoned to 0xAA before every timed launch; zero it first.
    hipMemsetAsync(out, 0, sizeof(float), stream);

    dim3 grid(NCHNK * 2, NIMG);    // (28, 32) = 896 blocks x 4 waves
    ssim_kernel<<<grid, dim3(NT), 0, stream>>>(x, y, w, out);
}